// Round 12
// baseline (1938.278 us; speedup 1.0000x reference)
//
#include <hip/hip_runtime.h>
#include <hip/hip_bf16.h>

#define N_NODES 20000
#define N_EDGES 320000
#define HIDDEN  128
#define NHEAD   4
#define NLAYER  4
#define NGRAPH  1024
#define OUTD    256
#define NBOND   400   // 20*10*2 distinct bond feature combos

typedef unsigned int u32;
typedef unsigned short u16;

// ---------------- fallback diagnostic: absmax ~= tag (f32 out) ----------------
__global__ __launch_bounds__(256) void fallback_out(float* __restrict__ out,
                                                    float tag, int n) {
    int i = blockIdx.x * 256 + threadIdx.x;
    if (i < n) out[i] = (i == 0 ? tag : 0.f);
}

__global__ __launch_bounds__(256) void zero_u32(u32* __restrict__ p, int n) {
    int i = blockIdx.x * 256 + threadIdx.x;
    if (i < n) p[i] = 0u;
}

// ---------------- encoders (pure f32) ----------------
__global__ __launch_bounds__(256) void atom_encode(const float* __restrict__ table,
                                                   const int* __restrict__ x,
                                                   float* __restrict__ h) {
    int t = threadIdx.x;
    int n = blockIdx.x * 4 + (t >> 6);
    if (n >= N_NODES) return;
    int c2 = t & 63;
    const int off[9] = {0,120,130,142,154,164,170,180,182};
    float a0 = 0.f, a1 = 0.f;
#pragma unroll
    for (int f = 0; f < 9; f++) {
        int idx = x[n*9 + f] + off[f];
        float2 w = *(const float2*)(table + (size_t)idx*128 + c2*2);
        a0 += w.x; a1 += w.y;
    }
    *(float2*)(h + (size_t)n*128 + c2*2) = make_float2(a0, a1);
}

// code[e] = ((a0*10)+a1)*2+a2  in [0,400)
__global__ __launch_bounds__(256) void edge_code(const int* __restrict__ ea,
                                                 int* __restrict__ code) {
    int e = blockIdx.x * 256 + threadIdx.x;
    if (e >= N_EDGES) return;
    int c = (ea[e*3] * 10 + ea[e*3 + 1]) * 2 + ea[e*3 + 2];
    code[e] = max(0, min(c, NBOND - 1));
}

// bcomb[c][:] = T[a0] + T[20+a1] + T[30+a2]   (f32)
__global__ __launch_bounds__(256) void bond_combine(const float* __restrict__ table,
                                                    float* __restrict__ bcomb) {
    int t = threadIdx.x;
    int c = blockIdx.x * 4 + (t >> 6);
    if (c >= NBOND) return;
    int c2 = t & 63;
    int a2 = c & 1, a1 = (c >> 1) % 10, a0 = c / 20;
    float2 w0 = *(const float2*)(table + (size_t)a0*128 + c2*2);
    float2 w1 = *(const float2*)(table + (size_t)(20 + a1)*128 + c2*2);
    float2 w2 = *(const float2*)(table + (size_t)(30 + a2)*128 + c2*2);
    *(float2*)(bcomb + (size_t)c*128 + c2*2) =
        make_float2(w0.x + w1.x + w2.x, w0.y + w1.y + w2.y);
}

// ---------------- generic f32 GEMM: C[M,128] = A[M,128] @ W[128,128] (+bias)(+relu) ----------------
// W staged in two 64-row halves (32KB); A tile 32 rows (16KB). 256 threads.
__global__ __launch_bounds__(256) void gemm128f(const float* __restrict__ A,
                                                const float* __restrict__ W,
                                                const float* __restrict__ bias,
                                                float* __restrict__ C, int M, int relu) {
    __shared__ float Wl[64*128];   // 32 KB
    __shared__ float Al[32*128];   // 16 KB
    int t = threadIdx.x;
    int row0 = blockIdx.x * 32;
    int rows = min(32, M - row0);
    const float4* A4 = (const float4*)(A + (size_t)row0*128);
    float4* Al4 = (float4*)Al;
    for (int i = t; i < 1024; i += 256) {
        int r = i >> 5;
        Al4[i] = (r < rows) ? A4[i] : make_float4(0.f,0.f,0.f,0.f);
    }
    int cp = t & 63;   // column pair
    int rg = t >> 6;   // row group
    float acc0[8], acc1[8];
#pragma unroll
    for (int j = 0; j < 8; j++) { acc0[j] = 0.f; acc1[j] = 0.f; }
#pragma unroll
    for (int kh = 0; kh < 2; kh++) {
        __syncthreads();   // kh=0: Al ready; kh=1: Wl reads done
        const float4* W4 = (const float4*)(W + kh*64*128);
        float4* Wl4 = (float4*)Wl;
        for (int i = t; i < 2048; i += 256) Wl4[i] = W4[i];
        __syncthreads();
#pragma unroll 4
        for (int kk = 0; kk < 64; kk++) {
            float w0 = Wl[kk*128 + cp*2];
            float w1 = Wl[kk*128 + cp*2 + 1];
#pragma unroll
            for (int j = 0; j < 8; j++) {
                float a = Al[(j*4 + rg)*128 + kh*64 + kk];
                acc0[j] = fmaf(a, w0, acc0[j]);
                acc1[j] = fmaf(a, w1, acc1[j]);
            }
        }
    }
    float b0 = 0.f, b1 = 0.f;
    if (bias) { b0 = bias[cp*2]; b1 = bias[cp*2 + 1]; }
#pragma unroll
    for (int j = 0; j < 8; j++) {
        int r = row0 + j*4 + rg;
        if (r < M) {
            float v0 = acc0[j] + b0, v1 = acc1[j] + b1;
            if (relu) { v0 = fmaxf(v0, 0.f); v1 = fmaxf(v1, 0.f); }
            *(float2*)(C + (size_t)r*128 + cp*2) = make_float2(v0, v1);
        }
    }
}

// ---------------- segment-max float encoding ----------------
__device__ __forceinline__ u32 enc_f(float f) {
    u32 u = __float_as_uint(f);
    return (u & 0x80000000u) ? ~u : (u | 0x80000000u);
}
__device__ __forceinline__ float dec_f(u32 e) {
    return (e & 0x80000000u) ? __uint_as_float(e & 0x7FFFFFFFu) : __uint_as_float(~e);
}

// ---------------- edge pass A: logits + segment max ----------------
__global__ __launch_bounds__(256) void edge_logits(const float* __restrict__ q,
                                                   const float* __restrict__ k,
                                                   const float* __restrict__ eeTab,
                                                   const int* __restrict__ code,
                                                   const int* __restrict__ src,
                                                   const int* __restrict__ dst,
                                                   float* __restrict__ logits,
                                                   u32* __restrict__ mEnc, int E) {
    int t = threadIdx.x;
    int e = blockIdx.x * 4 + (t >> 6);
    if (e >= E) return;
    int lane = t & 63;
    int s = src[e], d = dst[e];
    float2 q2 = *(const float2*)(q + (size_t)d*128 + lane*2);
    float2 k2 = *(const float2*)(k + (size_t)s*128 + lane*2);
    float2 e2 = *(const float2*)(eeTab + (size_t)code[e]*128 + lane*2);
    float val = q2.x * (k2.x + e2.x) + q2.y * (k2.y + e2.y);
#pragma unroll
    for (int off = 8; off >= 1; off >>= 1) val += __shfl_xor(val, off, 64);
    if ((lane & 15) == 0) {
        int head = lane >> 4;
        float lg = val * 0.17677669529663687f; // 1/sqrt(32)
        logits[(size_t)e*NHEAD + head] = lg;
        atomicMax(&mEnc[d*NHEAD + head], enc_f(lg));
    }
}

// ---------------- edge pass B: p, z, scatter p*vj ----------------
__global__ __launch_bounds__(256) void edge_scatter(const float* __restrict__ v,
                                                    const float* __restrict__ eeTab,
                                                    const int* __restrict__ code,
                                                    const float* __restrict__ logits,
                                                    const u32* __restrict__ mEnc,
                                                    const int* __restrict__ src,
                                                    const int* __restrict__ dst,
                                                    float* __restrict__ z,
                                                    float* __restrict__ msg, int E) {
    int t = threadIdx.x;
    int e = blockIdx.x * 4 + (t >> 6);
    if (e >= E) return;
    int lane = t & 63;
    int head = lane >> 4;
    int s = src[e], d = dst[e];
    float m = dec_f(mEnc[d*NHEAD + head]);
    float p = expf(logits[(size_t)e*NHEAD + head] - m);
    if ((lane & 15) == 0) atomicAdd(&z[d*NHEAD + head], p);
    float2 v2 = *(const float2*)(v + (size_t)s*128 + lane*2);
    float2 e2 = *(const float2*)(eeTab + (size_t)code[e]*128 + lane*2);
    atomicAdd(&msg[(size_t)d*128 + lane*2],     p * (v2.x + e2.x));
    atomicAdd(&msg[(size_t)d*128 + lane*2 + 1], p * (v2.y + e2.y));
}

// ---------------- h update: hn = relu(msg/z + hn)  (hn holds skip) ----------------
__global__ __launch_bounds__(256) void update_h(const float* __restrict__ msg,
                                                const float* __restrict__ z,
                                                float* __restrict__ hn) {
    int i = blockIdx.x * 256 + threadIdx.x;
    if (i >= N_NODES*64) return;
    int n = i >> 6, c2 = i & 63;
    float zz = fmaxf(z[n*NHEAD + (c2 >> 4)], 1e-16f);
    float2 mg = *(const float2*)(msg + (size_t)n*128 + c2*2);
    float2 sk = *(const float2*)(hn + (size_t)n*128 + c2*2);
    float2 o;
    o.x = fmaxf(mg.x / zz + sk.x, 0.f);
    o.y = fmaxf(mg.y / zz + sk.y, 0.f);
    *(float2*)(hn + (size_t)n*128 + c2*2) = o;
}

// ---------------- pooling ----------------
__global__ __launch_bounds__(256) void pool_scatter(const float* __restrict__ h,
                                                    const int* __restrict__ batch,
                                                    float* __restrict__ gsum,
                                                    float* __restrict__ gcnt) {
    int t = threadIdx.x;
    int n = blockIdx.x * 4 + (t >> 6);
    if (n >= N_NODES) return;
    int c2 = t & 63;
    int b = batch[n];
    float2 hv = *(const float2*)(h + (size_t)n*128 + c2*2);
    atomicAdd(&gsum[b*HIDDEN + c2*2],     hv.x);
    atomicAdd(&gsum[b*HIDDEN + c2*2 + 1], hv.y);
    if (c2 == 0) atomicAdd(&gcnt[b], 1.0f);
}

__global__ __launch_bounds__(256) void pool_finalize(float* __restrict__ gsum,
                                                     const float* __restrict__ gcnt) {
    int i = blockIdx.x * 256 + threadIdx.x;
    if (i >= NGRAPH*HIDDEN) return;
    int b = i >> 7;
    gsum[i] = gsum[i] / fmaxf(gcnt[b], 1.0f);
}

// ---------------- MLP2 + L2 normalize, f32 out ----------------
__global__ __launch_bounds__(256) void mlp2_norm(const float* __restrict__ g1,
                                                 const float* __restrict__ W2,
                                                 const float* __restrict__ b2,
                                                 float* __restrict__ out) {
    __shared__ float a[128];
    __shared__ float red[4];
    int b = blockIdx.x;
    int t = threadIdx.x;
    if (t < 128) a[t] = g1[b*128 + t];
    __syncthreads();
    float acc = 0.f;
#pragma unroll 4
    for (int kk = 0; kk < 128; kk++)
        acc = fmaf(a[kk], W2[kk*OUTD + t], acc);
    acc += b2[t];
    float sq = acc * acc;
#pragma unroll
    for (int off = 32; off >= 1; off >>= 1) sq += __shfl_xor(sq, off, 64);
    if ((t & 63) == 0) red[t >> 6] = sq;
    __syncthreads();
    float tot = red[0] + red[1] + red[2] + red[3];
    float rn = 1.0f / fmaxf(sqrtf(tot), 1e-12f);
    out[b*OUTD + t] = acc * rn;
}

extern "C" void kernel_launch(void* const* d_in, const int* in_sizes, int n_in,
                              void* d_out, int out_size, void* d_ws, size_t ws_size,
                              hipStream_t stream) {
    // ---- input-shape validation (host side, free) ----
    static const int EXP_SIZES[19] = {
        23552, 4096,                     // atom_table, bond_table
        65536, 512, 65536, 512, 65536, 512,  // Wq,bq,Wk,bk,Wv,bv
        65536, 65536, 512,               // We, Ws, bs
        16384, 128, 32768, 256,          // W1,b1,W2,b2
        180000, 960000, 640000, 20000    // x, edge_attr, edge_index, batch
    };
    if (n_in < 19 || out_size != NGRAPH*OUTD) {
        fallback_out<<<(out_size + 255) / 256, 256, 0, stream>>>(
            (float*)d_out, 9000.f, out_size);
        return;
    }
    for (int i = 0; i < 19; i++) {
        if (in_sizes[i] != EXP_SIZES[i]) {
            fallback_out<<<(out_size + 255) / 256, 256, 0, stream>>>(
                (float*)d_out, 100.f * (i + 1), out_size);
            return;
        }
    }

    const float* atomT = (const float*)d_in[0];
    const float* bondT = (const float*)d_in[1];
    const float* Wq = (const float*)d_in[2];
    const float* bq = (const float*)d_in[3];
    const float* Wk = (const float*)d_in[4];
    const float* bk = (const float*)d_in[5];
    const float* Wv = (const float*)d_in[6];
    const float* bv = (const float*)d_in[7];
    const float* We = (const float*)d_in[8];
    const float* Wsk= (const float*)d_in[9];
    const float* bsk= (const float*)d_in[10];
    const float* W1 = (const float*)d_in[11];
    const float* b1 = (const float*)d_in[12];
    const float* W2 = (const float*)d_in[13];
    const float* b2 = (const float*)d_in[14];
    const int* x          = (const int*)d_in[15];
    const int* edge_attr  = (const int*)d_in[16];
    const int* edge_index = (const int*)d_in[17];
    const int* batch      = (const int*)d_in[18];

    // ---- workspace layout (u32/float units) ----
    const size_t NEEDED_U32 =
        (size_t)N_NODES*128*5     /* h0,h1,qb,kb,vb */
      + (size_t)N_EDGES*NHEAD     /* logits  */
      + (size_t)N_EDGES           /* code    */
      + (size_t)N_NODES*NHEAD*2   /* mEnc,z  */
      + (size_t)N_NODES*128       /* msg     */
      + (size_t)NBOND*128*2       /* bcomb, eeTab */
      + (size_t)NGRAPH*HIDDEN*2 + NGRAPH; /* gsum,gcnt,g1 */
    if (ws_size < NEEDED_U32 * 4) {
        fallback_out<<<(out_size + 255) / 256, 256, 0, stream>>>(
            (float*)d_out, 50.f + (float)(ws_size >> 20) * 0.001f, out_size);
        return;
    }

    float* ws = (float*)d_ws;
    float* h0    = ws; ws += (size_t)N_NODES*128;
    float* h1    = ws; ws += (size_t)N_NODES*128;
    float* qb    = ws; ws += (size_t)N_NODES*128;
    float* kb    = ws; ws += (size_t)N_NODES*128;
    float* vb    = ws; ws += (size_t)N_NODES*128;
    float* logits= ws; ws += (size_t)N_EDGES*NHEAD;
    int*   code  = (int*)ws; ws += (size_t)N_EDGES;
    u32*   mEnc  = (u32*)ws; ws += (size_t)N_NODES*NHEAD;   // contiguous: mEnc, z, msg
    float* zb    = ws; ws += (size_t)N_NODES*NHEAD;
    float* msg   = ws; ws += (size_t)N_NODES*128;
    float* bcomb = ws; ws += (size_t)NBOND*128;
    float* eeTab = ws; ws += (size_t)NBOND*128;
    float* gsum  = ws; ws += (size_t)NGRAPH*HIDDEN;          // contiguous: gsum, gcnt
    float* gcnt  = ws; ws += (size_t)NGRAPH;
    float* g1    = ws; ws += (size_t)NGRAPH*HIDDEN;

    const int* srcp = edge_index;
    const int* dstp = edge_index + N_EDGES;

    atom_encode<<<(N_NODES + 3) / 4, 256, 0, stream>>>(atomT, x, h0);
    edge_code<<<(N_EDGES + 255) / 256, 256, 0, stream>>>(edge_attr, code);
    bond_combine<<<(NBOND + 3) / 4, 256, 0, stream>>>(bondT, bcomb);

    float* hc = h0;
    float* hn = h1;
    const int nodeBlocks = (N_NODES + 31) / 32;
    const int zeroN = N_NODES*NHEAD*2 + N_NODES*128;   // mEnc + z + msg
    for (int l = 0; l < NLAYER; l++) {
        gemm128f<<<nodeBlocks, 256, 0, stream>>>(hc, Wq + l*16384, bq + l*128, qb, N_NODES, 0);
        gemm128f<<<nodeBlocks, 256, 0, stream>>>(hc, Wk + l*16384, bk + l*128, kb, N_NODES, 0);
        gemm128f<<<nodeBlocks, 256, 0, stream>>>(hc, Wv + l*16384, bv + l*128, vb, N_NODES, 0);
        gemm128f<<<nodeBlocks, 256, 0, stream>>>(hc, Wsk + l*16384, bsk + l*128, hn, N_NODES, 0);
        gemm128f<<<(NBOND + 31) / 32, 256, 0, stream>>>(bcomb, We + l*16384, nullptr, eeTab, NBOND, 0);
        zero_u32<<<(zeroN + 255) / 256, 256, 0, stream>>>(mEnc, zeroN);
        edge_logits<<<(N_EDGES + 3) / 4, 256, 0, stream>>>(qb, kb, eeTab, code, srcp, dstp, logits, mEnc, N_EDGES);
        edge_scatter<<<(N_EDGES + 3) / 4, 256, 0, stream>>>(vb, eeTab, code, logits, mEnc, srcp, dstp, zb, msg, N_EDGES);
        update_h<<<(N_NODES*64 + 255) / 256, 256, 0, stream>>>(msg, zb, hn);
        float* tmp = hc; hc = hn; hn = tmp;
    }

    zero_u32<<<(NGRAPH*HIDDEN + NGRAPH + 255) / 256, 256, 0, stream>>>((u32*)gsum, NGRAPH*HIDDEN + NGRAPH);
    pool_scatter<<<(N_NODES + 3) / 4, 256, 0, stream>>>(hc, batch, gsum, gcnt);
    pool_finalize<<<(NGRAPH*HIDDEN + 255) / 256, 256, 0, stream>>>(gsum, gcnt);
    gemm128f<<<(NGRAPH + 31) / 32, 256, 0, stream>>>(gsum, W1, b1, g1, NGRAPH, 1);
    mlp2_norm<<<NGRAPH, 256, 0, stream>>>(g1, W2, b2, (float*)d_out);
}

// Round 15
// 868.574 us; speedup vs baseline: 2.2316x; 2.2316x over previous
//
#include <hip/hip_runtime.h>
#include <hip/hip_bf16.h>

#define N_NODES 20000
#define N_EDGES 320000
#define HIDDEN  128
#define NHEAD   4
#define NLAYER  4
#define NGRAPH  1024
#define OUTD    256
#define NBOND   400   // 20*10*2 distinct bond feature combos

typedef unsigned int u32;

// ---------------- fallback diagnostic: absmax ~= tag (f32 out) ----------------
__global__ __launch_bounds__(256) void fallback_out(float* __restrict__ out,
                                                    float tag, int n) {
    int i = blockIdx.x * 256 + threadIdx.x;
    if (i < n) out[i] = (i == 0 ? tag : 0.f);
}

__global__ __launch_bounds__(256) void zero_u32(u32* __restrict__ p, int n) {
    int i = blockIdx.x * 256 + threadIdx.x;
    if (i < n) p[i] = 0u;
}

// ---------------- encoders (pure f32) ----------------
__global__ __launch_bounds__(256) void atom_encode(const float* __restrict__ table,
                                                   const int* __restrict__ x,
                                                   float* __restrict__ h) {
    int t = threadIdx.x;
    int n = blockIdx.x * 4 + (t >> 6);
    if (n >= N_NODES) return;
    int c2 = t & 63;
    const int off[9] = {0,120,130,142,154,164,170,180,182};
    float a0 = 0.f, a1 = 0.f;
#pragma unroll
    for (int f = 0; f < 9; f++) {
        int idx = x[n*9 + f] + off[f];
        float2 w = *(const float2*)(table + (size_t)idx*128 + c2*2);
        a0 += w.x; a1 += w.y;
    }
    *(float2*)(h + (size_t)n*128 + c2*2) = make_float2(a0, a1);
}

// bcomb[c][:] = T[a0] + T[20+a1] + T[30+a2]   (f32)
__global__ __launch_bounds__(256) void bond_combine(const float* __restrict__ table,
                                                    float* __restrict__ bcomb) {
    int t = threadIdx.x;
    int c = blockIdx.x * 4 + (t >> 6);
    if (c >= NBOND) return;
    int c2 = t & 63;
    int a2 = c & 1, a1 = (c >> 1) % 10, a0 = c / 20;
    float2 w0 = *(const float2*)(table + (size_t)a0*128 + c2*2);
    float2 w1 = *(const float2*)(table + (size_t)(20 + a1)*128 + c2*2);
    float2 w2 = *(const float2*)(table + (size_t)(30 + a2)*128 + c2*2);
    *(float2*)(bcomb + (size_t)c*128 + c2*2) =
        make_float2(w0.x + w1.x + w2.x, w0.y + w1.y + w2.y);
}

__device__ __forceinline__ int bond_code(const int* __restrict__ ea, int e) {
    int c = (ea[e*3] * 10 + ea[e*3 + 1]) * 2 + ea[e*3 + 2];
    return max(0, min(c, NBOND - 1));
}

// ---------------- CSR build (once per call) ----------------
__global__ __launch_bounds__(256) void count_deg(const int* __restrict__ dst,
                                                 int* __restrict__ deg) {
    int e = blockIdx.x * 256 + threadIdx.x;
    if (e >= N_EDGES) return;
    atomicAdd(&deg[dst[e]], 1);
}

// single block, 256 threads: exclusive scan of deg -> rowptr; rowptr[N]=E
__global__ __launch_bounds__(256) void csr_scan(const int* __restrict__ deg,
                                                int* __restrict__ rowptr) {
    __shared__ int part[256];
    __shared__ int base[256];
    int t = threadIdx.x;
    const int CH = (N_NODES + 255) / 256;
    int lo = t * CH, hi = min(lo + CH, N_NODES);
    int s = 0;
    for (int i = lo; i < hi; i++) s += deg[i];
    part[t] = s;
    __syncthreads();
    if (t == 0) {
        int acc = 0;
        for (int i = 0; i < 256; i++) { base[i] = acc; acc += part[i]; }
        rowptr[N_NODES] = acc;
    }
    __syncthreads();
    int acc = base[t];
    for (int i = lo; i < hi; i++) { rowptr[i] = acc; acc += deg[i]; }
}

__global__ __launch_bounds__(256) void csr_fill(const int* __restrict__ src,
                                                const int* __restrict__ dst,
                                                const int* __restrict__ ea,
                                                const int* __restrict__ rowptr,
                                                int* __restrict__ fill,
                                                int* __restrict__ csrc,
                                                int* __restrict__ ccode) {
    int e = blockIdx.x * 256 + threadIdx.x;
    if (e >= N_EDGES) return;
    int d = dst[e];
    int pos = rowptr[d] + atomicAdd(&fill[d], 1);
    csrc[pos] = src[e];
    ccode[pos] = bond_code(ea, e);
}

// ---------------- generic f32 GEMM: C[M,128] = A[M,128] @ W[128,128] (+bias)(+relu) ----------------
__global__ __launch_bounds__(256) void gemm128f(const float* __restrict__ A,
                                                const float* __restrict__ W,
                                                const float* __restrict__ bias,
                                                float* __restrict__ C, int M, int relu) {
    __shared__ float Wl[64*128];   // 32 KB
    __shared__ float Al[32*128];   // 16 KB
    int t = threadIdx.x;
    int row0 = blockIdx.x * 32;
    int rows = min(32, M - row0);
    const float4* A4 = (const float4*)(A + (size_t)row0*128);
    float4* Al4 = (float4*)Al;
    for (int i = t; i < 1024; i += 256) {
        int r = i >> 5;
        Al4[i] = (r < rows) ? A4[i] : make_float4(0.f,0.f,0.f,0.f);
    }
    int cp = t & 63;   // column pair
    int rg = t >> 6;   // row group
    float acc0[8], acc1[8];
#pragma unroll
    for (int j = 0; j < 8; j++) { acc0[j] = 0.f; acc1[j] = 0.f; }
#pragma unroll
    for (int kh = 0; kh < 2; kh++) {
        __syncthreads();
        const float4* W4 = (const float4*)(W + kh*64*128);
        float4* Wl4 = (float4*)Wl;
        for (int i = t; i < 2048; i += 256) Wl4[i] = W4[i];
        __syncthreads();
#pragma unroll 4
        for (int kk = 0; kk < 64; kk++) {
            float w0 = Wl[kk*128 + cp*2];
            float w1 = Wl[kk*128 + cp*2 + 1];
#pragma unroll
            for (int j = 0; j < 8; j++) {
                float a = Al[(j*4 + rg)*128 + kh*64 + kk];
                acc0[j] = fmaf(a, w0, acc0[j]);
                acc1[j] = fmaf(a, w1, acc1[j]);
            }
        }
    }
    float b0 = 0.f, b1 = 0.f;
    if (bias) { b0 = bias[cp*2]; b1 = bias[cp*2 + 1]; }
#pragma unroll
    for (int j = 0; j < 8; j++) {
        int r = row0 + j*4 + rg;
        if (r < M) {
            float v0 = acc0[j] + b0, v1 = acc1[j] + b1;
            if (relu) { v0 = fmaxf(v0, 0.f); v1 = fmaxf(v1, 0.f); }
            *(float2*)(C + (size_t)r*128 + cp*2) = make_float2(v0, v1);
        }
    }
}

// ---------------- fused node GEMM: q,k,v,skip in one kernel (A-tile loaded once) ----------------
__global__ __launch_bounds__(256) void gemm_qkvs4(const float* __restrict__ A,
                                                  const float* __restrict__ Wq, const float* __restrict__ Wk,
                                                  const float* __restrict__ Wv, const float* __restrict__ Wsk,
                                                  const float* __restrict__ bq, const float* __restrict__ bk,
                                                  const float* __restrict__ bv, const float* __restrict__ bsk,
                                                  float* __restrict__ Cq, float* __restrict__ Ck,
                                                  float* __restrict__ Cv, float* __restrict__ Csk,
                                                  int M) {
    __shared__ float Wl[64*128];   // 32 KB
    __shared__ float Al[32*128];   // 16 KB
    int t = threadIdx.x;
    int row0 = blockIdx.x * 32;
    int rows = min(32, M - row0);
    const float4* A4 = (const float4*)(A + (size_t)row0*128);
    float4* Al4 = (float4*)Al;
    for (int i = t; i < 1024; i += 256) {
        int r = i >> 5;
        Al4[i] = (r < rows) ? A4[i] : make_float4(0.f,0.f,0.f,0.f);
    }
    const float* Wlist[4] = {Wq, Wk, Wv, Wsk};
    const float* blist[4] = {bq, bk, bv, bsk};
    float* Clist[4] = {Cq, Ck, Cv, Csk};
    int cp = t & 63;   // column pair
    int rg = t >> 6;   // row group
#pragma unroll
    for (int w = 0; w < 4; w++) {
        float acc0[8], acc1[8];
#pragma unroll
        for (int j = 0; j < 8; j++) { acc0[j] = 0.f; acc1[j] = 0.f; }
#pragma unroll
        for (int kh = 0; kh < 2; kh++) {
            __syncthreads();   // Al ready (first) / prior Wl reads done
            const float4* W4 = (const float4*)(Wlist[w] + kh*64*128);
            float4* Wl4 = (float4*)Wl;
            for (int i = t; i < 2048; i += 256) Wl4[i] = W4[i];
            __syncthreads();
#pragma unroll 4
            for (int kk = 0; kk < 64; kk++) {
                float w0 = Wl[kk*128 + cp*2];
                float w1 = Wl[kk*128 + cp*2 + 1];
#pragma unroll
                for (int j = 0; j < 8; j++) {
                    float a = Al[(j*4 + rg)*128 + kh*64 + kk];
                    acc0[j] = fmaf(a, w0, acc0[j]);
                    acc1[j] = fmaf(a, w1, acc1[j]);
                }
            }
        }
        float b0 = blist[w][cp*2], b1 = blist[w][cp*2 + 1];
        float* C = Clist[w];
#pragma unroll
        for (int j = 0; j < 8; j++) {
            int r = row0 + j*4 + rg;
            if (r < M)
                *(float2*)(C + (size_t)r*128 + cp*2) = make_float2(acc0[j] + b0, acc1[j] + b1);
        }
    }
}

// ---------------- fused attention aggregate: one wave per node, no atomics ----------------
__global__ __launch_bounds__(256) void edge_attn(const float* __restrict__ q,
                                                 const float* __restrict__ k,
                                                 const float* __restrict__ v,
                                                 const float* __restrict__ eeTab,
                                                 const int* __restrict__ rowptr,
                                                 const int* __restrict__ csrc,
                                                 const int* __restrict__ ccode,
                                                 float* __restrict__ plog,
                                                 float* __restrict__ hn) {
    int t = threadIdx.x;
    int n = blockIdx.x * 4 + (t >> 6);
    if (n >= N_NODES) return;
    int lane = t & 63;
    int head = lane >> 4;
    int beg = rowptr[n], end = rowptr[n + 1];
    float2 q2 = *(const float2*)(q + (size_t)n*128 + lane*2);
    float m = -3.4e38f;
    for (int j = beg; j < end; j++) {
        int s = csrc[j], cb = ccode[j];
        float2 k2 = *(const float2*)(k + (size_t)s*128 + lane*2);
        float2 e2 = *(const float2*)(eeTab + (size_t)cb*128 + lane*2);
        float val = q2.x*(k2.x + e2.x) + q2.y*(k2.y + e2.y);
#pragma unroll
        for (int off = 8; off >= 1; off >>= 1) val += __shfl_xor(val, off, 64);
        float lg = val * 0.17677669529663687f; // 1/sqrt(32)
        plog[(size_t)j*4 + head] = lg;   // all 16 lanes store same value -> own-store coherence
        m = fmaxf(m, lg);
    }
    float zacc = 0.f, a0 = 0.f, a1 = 0.f;
    for (int j = beg; j < end; j++) {
        int s = csrc[j], cb = ccode[j];
        float p = expf(plog[(size_t)j*4 + head] - m);
        float2 v2 = *(const float2*)(v + (size_t)s*128 + lane*2);
        float2 e2 = *(const float2*)(eeTab + (size_t)cb*128 + lane*2);
        zacc += p;
        a0 = fmaf(p, v2.x + e2.x, a0);
        a1 = fmaf(p, v2.y + e2.y, a1);
    }
    float rz = 1.0f / fmaxf(zacc, 1e-16f);
    float2 sk = *(const float2*)(hn + (size_t)n*128 + lane*2);
    float2 o;
    o.x = fmaxf(fmaf(a0, rz, sk.x), 0.f);
    o.y = fmaxf(fmaf(a1, rz, sk.y), 0.f);
    *(float2*)(hn + (size_t)n*128 + lane*2) = o;
}

// ---------------- pooling ----------------
__global__ __launch_bounds__(256) void pool_scatter(const float* __restrict__ h,
                                                    const int* __restrict__ batch,
                                                    float* __restrict__ gsum,
                                                    float* __restrict__ gcnt) {
    int t = threadIdx.x;
    int n = blockIdx.x * 4 + (t >> 6);
    if (n >= N_NODES) return;
    int c2 = t & 63;
    int b = batch[n];
    float2 hv = *(const float2*)(h + (size_t)n*128 + c2*2);
    atomicAdd(&gsum[b*HIDDEN + c2*2],     hv.x);
    atomicAdd(&gsum[b*HIDDEN + c2*2 + 1], hv.y);
    if (c2 == 0) atomicAdd(&gcnt[b], 1.0f);
}

__global__ __launch_bounds__(256) void pool_finalize(float* __restrict__ gsum,
                                                     const float* __restrict__ gcnt) {
    int i = blockIdx.x * 256 + threadIdx.x;
    if (i >= NGRAPH*HIDDEN) return;
    int b = i >> 7;
    gsum[i] = gsum[i] / fmaxf(gcnt[b], 1.0f);
}

// ---------------- MLP2 + L2 normalize, f32 out ----------------
__global__ __launch_bounds__(256) void mlp2_norm(const float* __restrict__ g1,
                                                 const float* __restrict__ W2,
                                                 const float* __restrict__ b2,
                                                 float* __restrict__ out) {
    __shared__ float a[128];
    __shared__ float red[4];
    int b = blockIdx.x;
    int t = threadIdx.x;
    if (t < 128) a[t] = g1[b*128 + t];
    __syncthreads();
    float acc = 0.f;
#pragma unroll 4
    for (int kk = 0; kk < 128; kk++)
        acc = fmaf(a[kk], W2[kk*OUTD + t], acc);
    acc += b2[t];
    float sq = acc * acc;
#pragma unroll
    for (int off = 32; off >= 1; off >>= 1) sq += __shfl_xor(sq, off, 64);
    if ((t & 63) == 0) red[t >> 6] = sq;
    __syncthreads();
    float tot = red[0] + red[1] + red[2] + red[3];
    float rn = 1.0f / fmaxf(sqrtf(tot), 1e-12f);
    out[b*OUTD + t] = acc * rn;
}

extern "C" void kernel_launch(void* const* d_in, const int* in_sizes, int n_in,
                              void* d_out, int out_size, void* d_ws, size_t ws_size,
                              hipStream_t stream) {
    static const int EXP_SIZES[19] = {
        23552, 4096,
        65536, 512, 65536, 512, 65536, 512,
        65536, 65536, 512,
        16384, 128, 32768, 256,
        180000, 960000, 640000, 20000
    };
    if (n_in < 19 || out_size != NGRAPH*OUTD) {
        fallback_out<<<(out_size + 255) / 256, 256, 0, stream>>>(
            (float*)d_out, 9000.f, out_size);
        return;
    }
    for (int i = 0; i < 19; i++) {
        if (in_sizes[i] != EXP_SIZES[i]) {
            fallback_out<<<(out_size + 255) / 256, 256, 0, stream>>>(
                (float*)d_out, 100.f * (i + 1), out_size);
            return;
        }
    }

    const float* atomT = (const float*)d_in[0];
    const float* bondT = (const float*)d_in[1];
    const float* Wq = (const float*)d_in[2];
    const float* bq = (const float*)d_in[3];
    const float* Wk = (const float*)d_in[4];
    const float* bk = (const float*)d_in[5];
    const float* Wv = (const float*)d_in[6];
    const float* bv = (const float*)d_in[7];
    const float* We = (const float*)d_in[8];
    const float* Wsk= (const float*)d_in[9];
    const float* bsk= (const float*)d_in[10];
    const float* W1 = (const float*)d_in[11];
    const float* b1 = (const float*)d_in[12];
    const float* W2 = (const float*)d_in[13];
    const float* b2 = (const float*)d_in[14];
    const int* x          = (const int*)d_in[15];
    const int* edge_attr  = (const int*)d_in[16];
    const int* edge_index = (const int*)d_in[17];
    const int* batch      = (const int*)d_in[18];

    // ---- workspace layout (u32 units) ----
    const size_t NEEDED_U32 =
        (size_t)N_NODES*128*5     /* h0,h1,qb,kb,vb */
      + (size_t)N_EDGES*NHEAD     /* plog    */
      + (size_t)N_NODES*2 + (N_NODES + 1) /* deg, fill, rowptr */
      + (size_t)N_EDGES*2         /* csrc, ccode */
      + (size_t)NBOND*128*2       /* bcomb, eeTab */
      + (size_t)NGRAPH*HIDDEN*2 + NGRAPH; /* gsum,gcnt,g1 */
    if (ws_size < NEEDED_U32 * 4) {
        fallback_out<<<(out_size + 255) / 256, 256, 0, stream>>>(
            (float*)d_out, 50.f + (float)(ws_size >> 20) * 0.001f, out_size);
        return;
    }

    float* ws = (float*)d_ws;
    float* h0    = ws; ws += (size_t)N_NODES*128;
    float* h1    = ws; ws += (size_t)N_NODES*128;
    float* qb    = ws; ws += (size_t)N_NODES*128;
    float* kb    = ws; ws += (size_t)N_NODES*128;
    float* vb    = ws; ws += (size_t)N_NODES*128;
    float* plog  = ws; ws += (size_t)N_EDGES*NHEAD;
    int*   deg   = (int*)ws; ws += (size_t)N_NODES;      // contiguous: deg, fill
    int*   fill  = (int*)ws; ws += (size_t)N_NODES;
    int*   rowptr= (int*)ws; ws += (size_t)(N_NODES + 1);
    int*   csrc  = (int*)ws; ws += (size_t)N_EDGES;
    int*   ccode = (int*)ws; ws += (size_t)N_EDGES;
    float* bcomb = ws; ws += (size_t)NBOND*128;
    float* eeTab = ws; ws += (size_t)NBOND*128;
    float* gsum  = ws; ws += (size_t)NGRAPH*HIDDEN;      // contiguous: gsum, gcnt
    float* gcnt  = ws; ws += (size_t)NGRAPH;
    float* g1    = ws; ws += (size_t)NGRAPH*HIDDEN;

    const int* srcp = edge_index;
    const int* dstp = edge_index + N_EDGES;

    // ---- CSR build (once) ----
    zero_u32<<<(N_NODES*2 + 255) / 256, 256, 0, stream>>>((u32*)deg, N_NODES*2);
    count_deg<<<(N_EDGES + 255) / 256, 256, 0, stream>>>(dstp, deg);
    csr_scan<<<1, 256, 0, stream>>>(deg, rowptr);
    csr_fill<<<(N_EDGES + 255) / 256, 256, 0, stream>>>(srcp, dstp, edge_attr, rowptr, fill, csrc, ccode);

    atom_encode<<<(N_NODES + 3) / 4, 256, 0, stream>>>(atomT, x, h0);
    bond_combine<<<(NBOND + 3) / 4, 256, 0, stream>>>(bondT, bcomb);

    float* hc = h0;
    float* hn = h1;
    const int nodeBlocks = (N_NODES + 31) / 32;
    const int attnBlocks = (N_NODES + 3) / 4;
    for (int l = 0; l < NLAYER; l++) {
        gemm_qkvs4<<<nodeBlocks, 256, 0, stream>>>(hc,
            Wq + l*16384, Wk + l*16384, Wv + l*16384, Wsk + l*16384,
            bq + l*128, bk + l*128, bv + l*128, bsk + l*128,
            qb, kb, vb, hn, N_NODES);
        gemm128f<<<(NBOND + 31) / 32, 256, 0, stream>>>(bcomb, We + l*16384, nullptr, eeTab, NBOND, 0);
        edge_attn<<<attnBlocks, 256, 0, stream>>>(qb, kb, vb, eeTab, rowptr, csrc, ccode, plog, hn);
        float* tmp = hc; hc = hn; hn = tmp;
    }

    zero_u32<<<(NGRAPH*HIDDEN + NGRAPH + 255) / 256, 256, 0, stream>>>((u32*)gsum, NGRAPH*HIDDEN + NGRAPH);
    pool_scatter<<<(N_NODES + 3) / 4, 256, 0, stream>>>(hc, batch, gsum, gcnt);
    pool_finalize<<<(NGRAPH*HIDDEN + 255) / 256, 256, 0, stream>>>(gsum, gcnt);
    gemm128f<<<(NGRAPH + 31) / 32, 256, 0, stream>>>(gsum, W1, b1, g1, NGRAPH, 1);
    mlp2_norm<<<NGRAPH, 256, 0, stream>>>(g1, W2, b2, (float*)d_out);
}